// Round 6
// baseline (11123.257 us; speedup 1.0000x reference)
//
#include <hip/hip_runtime.h>
#include <stdint.h>

#define SEQ 512
#define BAT 64
#define INF 256     // input features
#define HID 1024
#define SB  (SEQ*BAT)   // 32768 rows
#define G_WGS 64            // WGs per pipeline group
#define NWG (3*G_WGS)       // 192 persistent WGs

typedef __attribute__((ext_vector_type(8))) short short8;
typedef __attribute__((ext_vector_type(4))) float f32x4;

union Frag8 { uint32_t u[4]; short8 s; };

// ---------- numeric helpers: fp32 <-> (bf16 hi, bf16 lo) ----------
__device__ __forceinline__ uint32_t bf16hi_rne(uint32_t u){
  return (u + 0x7FFFu + ((u >> 16) & 1u)) & 0xFFFF0000u;
}
__device__ __forceinline__ uint32_t pack_split(float v){
  uint32_t hi = bf16hi_rne(__float_as_uint(v));
  float r = v - __uint_as_float(hi);
  uint32_t lo = bf16hi_rne(__float_as_uint(r)) >> 16;
  return hi | lo;                              // (hi16<<16) | lo16
}
__device__ __forceinline__ void unpack_pair(uint32_t u0, uint32_t u1,
                                            uint32_t& h, uint32_t& l){
  h = __builtin_amdgcn_perm(u1, u0, 0x07060302u);  // {u0.b2,u0.b3,u1.b2,u1.b3}
  l = __builtin_amdgcn_perm(u1, u0, 0x05040100u);  // {u0.b0,u0.b1,u1.b0,u1.b1}
}
__device__ __forceinline__ void gl16(const void* g, void* l){
  __builtin_amdgcn_global_load_lds(
      (const __attribute__((address_space(1))) void*)g,
      (__attribute__((address_space(3))) void*)l, 16, 0, 0);
}

// ---------- relaxed agent-scope atomics ----------
__device__ __forceinline__ uint32_t aload32(const uint32_t* p){
  return __hip_atomic_load(p, __ATOMIC_RELAXED, __HIP_MEMORY_SCOPE_AGENT);
}
__device__ __forceinline__ uint64_t aload64(const uint64_t* p){
  return __hip_atomic_load(p, __ATOMIC_RELAXED, __HIP_MEMORY_SCOPE_AGENT);
}
__device__ __forceinline__ void astore32(uint32_t* p, uint32_t v){
  __hip_atomic_store(p, v, __ATOMIC_RELAXED, __HIP_MEMORY_SCOPE_AGENT);
}
__device__ __forceinline__ void waitctr(uint32_t* c, uint32_t tgt){
  unsigned spins = 0;
  while (__hip_atomic_load(c, __ATOMIC_RELAXED, __HIP_MEMORY_SCOPE_AGENT) < tgt){
    __builtin_amdgcn_s_sleep(2);
    if (++spins > (1u << 22)) break;   // failsafe: no hang
  }
}

// ---------- prep kernels ----------
__global__ __launch_bounds__(256) void wcomb_kernel(const float* __restrict__ A,
                                                    const float* __restrict__ B,
                                                    float* __restrict__ C){
  __shared__ float As[16][64];
  __shared__ float Bs[64][256];
  const int tid = threadIdx.x;
  const int g0 = blockIdx.x * 16;
  float acc[16];
#pragma unroll
  for (int g = 0; g < 16; ++g) acc[g] = 0.f;
  for (int h0 = 0; h0 < HID; h0 += 64){
    __syncthreads();
#pragma unroll
    for (int j = 0; j < 4; ++j){
      int c = j*256 + tid;
      As[c >> 6][c & 63] = A[(size_t)(g0 + (c >> 6))*HID + h0 + (c & 63)];
    }
#pragma unroll
    for (int j = 0; j < 64; ++j) Bs[j][tid] = B[(size_t)(h0 + j)*INF + tid];
    __syncthreads();
#pragma unroll
    for (int hh = 0; hh < 64; hh += 4){
      float b0 = Bs[hh][tid], b1 = Bs[hh+1][tid], b2 = Bs[hh+2][tid], b3 = Bs[hh+3][tid];
#pragma unroll
      for (int g = 0; g < 16; ++g){
        const float4 a = *(const float4*)&As[g][hh];
        acc[g] += a.x*b0 + a.y*b1 + a.z*b2 + a.w*b3;
      }
    }
  }
#pragma unroll
  for (int g = 0; g < 16; ++g) C[(size_t)(g0 + g)*INF + tid] = acc[g];
}

__global__ __launch_bounds__(256) void bcomb_kernel(const float* __restrict__ Wih0,
                                                    const float* __restrict__ bin,
                                                    const float* __restrict__ bih0,
                                                    float* __restrict__ bcomb){
  __shared__ float r[4];
  const int g = blockIdx.x, tid = threadIdx.x;
  float s = 0.f;
  for (int h = tid; h < HID; h += 256) s += Wih0[(size_t)g*HID + h] * bin[h];
  for (int o = 32; o > 0; o >>= 1) s += __shfl_down(s, o, 64);
  if ((tid & 63) == 0) r[tid >> 6] = s;
  __syncthreads();
  if (tid == 0) bcomb[g] = bih0[g] + r[0] + r[1] + r[2] + r[3];
}

__global__ void split_w(const float* __restrict__ in, uint16_t* __restrict__ hi,
                        uint16_t* __restrict__ lo, int n){
  int i = blockIdx.x*256 + threadIdx.x;
  if (i < n){
    float v = in[i];
    uint32_t h = bf16hi_rne(__float_as_uint(v));
    float r = v - __uint_as_float(h);
    hi[i] = (uint16_t)(h >> 16);
    lo[i] = (uint16_t)(bf16hi_rne(__float_as_uint(r)) >> 16);
  }
}

__global__ void pack_x(const float* __restrict__ in, uint32_t* __restrict__ out, int n){
  int i = blockIdx.x*256 + threadIdx.x;
  if (i < n) out[i] = pack_split(in[i]);
}

// ---------- batched split GEMM (pre0 / out): C = unpack(A) @ (Whi+Wlo)^T + bias ----------
__global__ __launch_bounds__(256) void gemm_split(
    const uint32_t* __restrict__ A, const uint16_t* __restrict__ Whi,
    const uint16_t* __restrict__ Wlo, const float* __restrict__ bias,
    float* __restrict__ C, int N, int K)
{
  __shared__ uint32_t Al[128*32];
  __shared__ uint16_t Wh[128*32];
  __shared__ uint16_t Wl[128*32];
  const int tid  = threadIdx.x;
  const int lane = tid & 63;
  const int w    = tid >> 6;
  const int wm   = w >> 1, wn = w & 1;
  const int lr   = lane & 15, kg = lane >> 4;
  const int bm   = blockIdx.x, bn = blockIdx.y;

  const uint32_t* Ag  = A   + (size_t)bm*128*K;
  const uint16_t* Whg = Whi + (size_t)bn*128*K;
  const uint16_t* Wlg = Wlo + (size_t)bn*128*K;

  f32x4 acc[4][4];
#pragma unroll
  for (int i = 0; i < 4; ++i)
#pragma unroll
    for (int j = 0; j < 4; ++j) acc[i][j] = (f32x4){0.f,0.f,0.f,0.f};

  for (int ks = 0; ks < K; ks += 32){
    __syncthreads();
#pragma unroll
    for (int j = 0; j < 4; ++j){
      int c = j*256 + tid;
      int row = c >> 3, kc = c & 7;
      int kcs = kc ^ ((row & 3) << 1);
      gl16(Ag + (size_t)row*K + ks + kcs*4, (char*)Al + c*16);
    }
#pragma unroll
    for (int j = 0; j < 2; ++j){
      int c = j*256 + tid;
      int row = c >> 2, kc = c & 3;
      int kcs = kc ^ (row & 3);
      gl16(Whg + (size_t)row*K + ks + kcs*8, (char*)Wh + c*16);
      gl16(Wlg + (size_t)row*K + ks + kcs*8, (char*)Wl + c*16);
    }
    __syncthreads();

    short8 ah[4], al[4];
#pragma unroll
    for (int mt = 0; mt < 4; ++mt){
      int row = wm*64 + mt*16 + lr;
      int c2  = kg ^ (row & 3);
      const uint32_t* p = &Al[row*32 + c2*8];
      uint4 a0 = *(const uint4*)p;
      uint4 a1 = *(const uint4*)(p + 4);
      Frag8 fh, fl;
      unpack_pair(a0.x, a0.y, fh.u[0], fl.u[0]);
      unpack_pair(a0.z, a0.w, fh.u[1], fl.u[1]);
      unpack_pair(a1.x, a1.y, fh.u[2], fl.u[2]);
      unpack_pair(a1.z, a1.w, fh.u[3], fl.u[3]);
      ah[mt] = fh.s; al[mt] = fl.s;
    }
#pragma unroll
    for (int nt = 0; nt < 4; ++nt){
      int row = wn*64 + nt*16 + lr;
      int kc  = kg ^ (row & 3);
      short8 whf = *(const short8*)&Wh[row*32 + kc*8];
      short8 wlf = *(const short8*)&Wl[row*32 + kc*8];
#pragma unroll
      for (int mt = 0; mt < 4; ++mt){
        acc[mt][nt] = __builtin_amdgcn_mfma_f32_16x16x32_bf16(ah[mt], whf, acc[mt][nt], 0,0,0);
        acc[mt][nt] = __builtin_amdgcn_mfma_f32_16x16x32_bf16(al[mt], whf, acc[mt][nt], 0,0,0);
        acc[mt][nt] = __builtin_amdgcn_mfma_f32_16x16x32_bf16(ah[mt], wlf, acc[mt][nt], 0,0,0);
      }
    }
  }
#pragma unroll
  for (int nt = 0; nt < 4; ++nt){
    int col = bn*128 + wn*64 + nt*16 + lr;
    float bv = bias[col];
#pragma unroll
    for (int mt = 0; mt < 4; ++mt){
#pragma unroll
      for (int r = 0; r < 4; ++r){
        int rowg = bm*128 + wm*64 + mt*16 + kg*4 + r;
        C[(size_t)rowg*N + col] = acc[mt][nt][r] + bv;
      }
    }
  }
}

// ---------- persistent wavefront scan, weights in LDS ----------
// 192 WGs x 256 thr (4 waves). group = wg/64: 0 = L0 recurrence (t=r),
// 1 = Wih1*h0 (t=r-1), 2 = L1 recurrence (t=r-2).
// sub = wg%64: rh = sub>>5 (32-row half), ci = sub&31 (32-col slice).
// Each wave: one 16x16 out tile (mt=w>>1, ntw=w&1), full K=1024, 4 acc chains.
// W slice (hi+lo) staged once into 128 KB LDS with 16B-chunk XOR swizzle.
__global__ __launch_bounds__(256, 1) void rnn_persist(
    float* buf0, float* buf1,
    const uint16_t* __restrict__ Whh0h, const uint16_t* __restrict__ Whh0l,
    const uint16_t* __restrict__ Wih1h, const uint16_t* __restrict__ Wih1l,
    const uint16_t* __restrict__ Whh1h, const uint16_t* __restrict__ Whh1l,
    const float* __restrict__ bhh0, const float* __restrict__ bih1,
    const float* __restrict__ bhh1,
    uint32_t* h0s, uint32_t* h1s,
    uint32_t* ctr, int T, int first)
{
  __shared__ short Wh[32*1024];   // 64 KB
  __shared__ short Wl[32*1024];   // 64 KB
  const int tid  = threadIdx.x;
  const int lane = tid & 63;
  const int w    = tid >> 6;                 // 0..3
  const int mt   = w >> 1, ntw = w & 1;
  const int lr   = lane & 15, kg = lane >> 4;
  const int wg   = blockIdx.x;
  const int group = wg / G_WGS;              // 0,1,2
  const int sub  = wg % G_WGS;
  const int rh   = sub >> 5;                 // 0..1 (rows 32*rh)
  const int ci   = sub & 31;                 // 0..31 (cols 32*ci)
  const int col0 = ci * 32;

  uint32_t* c0 = ctr;          // G0 step counter (64 per step)
  uint32_t* c1 = ctr + 64;     // G1
  uint32_t* c2 = ctr + 128;    // G2
  uint32_t* cmy = (group == 0) ? c0 : (group == 1) ? c1 : c2;

  const uint16_t* Whg = (group == 0) ? Whh0h : (group == 1) ? Wih1h : Whh1h;
  const uint16_t* Wlg = (group == 0) ? Whh0l : (group == 1) ? Wih1l : Whh1l;

  // ---- stage W slice into LDS (once), XOR-swizzled 16B chunks ----
#pragma unroll
  for (int it = 0; it < 16; ++it){
    int lin = it*256 + tid;          // 0..4095
    int c = lin >> 7, j = lin & 127; // row (col of W), 16B chunk
    int js = j ^ (c & 7);
    uint4 vh = *(const uint4*)&Whg[(size_t)(col0 + c)*HID + j*8];
    uint4 vl = *(const uint4*)&Wlg[(size_t)(col0 + c)*HID + j*8];
    *(uint4*)&Wh[c*1024 + js*8] = vh;
    *(uint4*)&Wl[c*1024 + js*8] = vl;
  }
  __syncthreads();

  const int wrow = ntw*16 + lr;            // W row within slice (0..31)
  const int rx   = wrow & 7;
  const short* WhR = &Wh[wrow*1024];
  const short* WlR = &Wl[wrow*1024];

  const int R = T + 2;
  for (int r = 0; r < R; ++r){
    const int t = r - group;
    const bool valid = (t >= 0 && t < T);

    // ---- dependency waits (relaxed polls) ----
    if (tid == 0){
      if (group == 0){
        if (valid && t > 0) waitctr(c0, 64u*(unsigned)t);
      } else if (group == 1){
        if (valid) waitctr(c0, 64u*(unsigned)(t+1));
      } else {
        if (valid){
          waitctr(c1, 64u*(unsigned)(t+1));
          if (t > 0) waitctr(c2, 64u*(unsigned)t);
        }
      }
    }
    __syncthreads();
    asm volatile("" ::: "memory");

    if (valid){
      const uint32_t* Ap;
      if (group == 0)
        Ap = (t == 0) ? (first ? (const uint32_t*)0 : h0s)
                      : (const uint32_t*)buf0 + (size_t)(t-1)*(BAT*HID);
      else if (group == 1)
        Ap = (const uint32_t*)buf0 + (size_t)t*(BAT*HID);
      else
        Ap = (t == 0) ? (first ? (const uint32_t*)0 : h1s)
                      : (const uint32_t*)buf1 + (size_t)(t-1)*(BAT*HID);

      f32x4 acc[4];
#pragma unroll
      for (int i = 0; i < 4; ++i) acc[i] = (f32x4){0.f,0.f,0.f,0.f};

      if (Ap){
        const int arow = rh*32 + mt*16 + lr;
        const uint64_t* Abase = (const uint64_t*)(Ap + (size_t)arow*HID) + kg*4;
#pragma unroll
        for (int kb = 0; kb < 4; ++kb){
#pragma unroll
          for (int k2 = 0; k2 < 8; ++k2){
            const int ks = kb*8 + k2;
            uint64_t q0 = aload64(Abase + ks*16 + 0);
            uint64_t q1 = aload64(Abase + ks*16 + 1);
            uint64_t q2 = aload64(Abase + ks*16 + 2);
            uint64_t q3 = aload64(Abase + ks*16 + 3);
            Frag8 fh, fl;
            unpack_pair((uint32_t)q0, (uint32_t)(q0 >> 32), fh.u[0], fl.u[0]);
            unpack_pair((uint32_t)q1, (uint32_t)(q1 >> 32), fh.u[1], fl.u[1]);
            unpack_pair((uint32_t)q2, (uint32_t)(q2 >> 32), fh.u[2], fl.u[2]);
            unpack_pair((uint32_t)q3, (uint32_t)(q3 >> 32), fh.u[3], fl.u[3]);
            const int js = (ks*4 + kg) ^ rx;
            short8 whf = *(const short8*)&WhR[js*8];
            short8 wlf = *(const short8*)&WlR[js*8];
            acc[kb] = __builtin_amdgcn_mfma_f32_16x16x32_bf16(fh.s, whf, acc[kb], 0,0,0);
            acc[kb] = __builtin_amdgcn_mfma_f32_16x16x32_bf16(fl.s, whf, acc[kb], 0,0,0);
            acc[kb] = __builtin_amdgcn_mfma_f32_16x16x32_bf16(fh.s, wlf, acc[kb], 0,0,0);
          }
        }
      }
      f32x4 s = (acc[0] + acc[1]) + (acc[2] + acc[3]);

      // ---- epilogue: D col = lane&15 -> our ntw*16+lr; row = kg*4+q ----
      const int col = col0 + ntw*16 + lr;
      if (group == 0){
        const float bv = bhh0[col];
#pragma unroll
        for (int q = 0; q < 4; ++q){
          const int row = rh*32 + mt*16 + kg*4 + q;
          const size_t idx = (size_t)t*(BAT*HID) + (size_t)row*HID + col;
          float v = tanhf(s[q] + buf0[idx] + bv);
          uint32_t pk = pack_split(v);
          astore32((uint32_t*)buf0 + idx, pk);
          if (t == T-1) astore32(h0s + (size_t)row*HID + col, pk);
        }
      } else if (group == 1){
        const float bv = bih1[col] + bhh1[col];
#pragma unroll
        for (int q = 0; q < 4; ++q){
          const int row = rh*32 + mt*16 + kg*4 + q;
          const size_t idx = (size_t)t*(BAT*HID) + (size_t)row*HID + col;
          astore32((uint32_t*)buf1 + idx, __float_as_uint(s[q] + bv));
        }
      } else {
#pragma unroll
        for (int q = 0; q < 4; ++q){
          const int row = rh*32 + mt*16 + kg*4 + q;
          const size_t idx = (size_t)t*(BAT*HID) + (size_t)row*HID + col;
          float pre = __uint_as_float(aload32((const uint32_t*)buf1 + idx));
          float v = tanhf(s[q] + pre);
          uint32_t pk = pack_split(v);
          astore32((uint32_t*)buf1 + idx, pk);
          if (t == T-1) astore32(h1s + (size_t)row*HID + col, pk);
        }
      }
    }

    // drain stores to the coherence point, then signal
    asm volatile("s_waitcnt vmcnt(0) lgkmcnt(0)" ::: "memory");
    __syncthreads();
    if (tid == 0 && valid)
      __hip_atomic_fetch_add(cmy, 1u, __ATOMIC_RELAXED, __HIP_MEMORY_SCOPE_AGENT);
  }
}

// ---------- hidden output from carried states ----------
__global__ void extract_hidden(const uint32_t* __restrict__ h0s,
                               const uint32_t* __restrict__ h1s,
                               float* __restrict__ out){
  int i = blockIdx.x*256 + threadIdx.x;   // 0..131071
  uint32_t p = (i >> 16) ? h1s[i & 65535] : h0s[i & 65535];
  out[(size_t)SB*INF + i] = __uint_as_float(p & 0xFFFF0000u) + __uint_as_float(p << 16);
}

// ---------- host ----------
extern "C" void kernel_launch(void* const* d_in, const int* in_sizes, int n_in,
                              void* d_out, int out_size, void* d_ws, size_t ws_size,
                              hipStream_t stream)
{
  const float* x    = (const float*)d_in[0];
  const float* W_in = (const float*)d_in[1];
  const float* b_in = (const float*)d_in[2];
  const float* W_ih = (const float*)d_in[3];   // [2][H][H]
  const float* W_hh = (const float*)d_in[4];   // [2][H][H]
  const float* b_ih = (const float*)d_in[5];   // [2][H]
  const float* b_hh = (const float*)d_in[6];   // [2][H]
  const float* W_out= (const float*)d_in[7];   // [I][H]
  const float* b_out= (const float*)d_in[8];
  float* out = (float*)d_out;
  (void)in_sizes; (void)n_in; (void)out_size;

  // ---- choose chunk length T to fit ws_size ----
  const size_t fixedB = 16257024 + 4096;
  const size_t perT   = 589824;
  int T = 512;
  while (T > 2 && fixedB + (size_t)T*perT + 65536 > ws_size) T >>= 1;
  const int nchunk = SEQ / T;

  char* ws = (char*)d_ws;
  size_t off = 0;
  auto alloc = [&](size_t bytes)->void*{
    void* p = ws + off; off += (bytes + 255) & ~(size_t)255; return p;
  };
  float*    buf0   = (float*)   alloc((size_t)T*BAT*HID*4);  // pre0 -> packed h0 (chunk)
  float*    buf1   = (float*)   alloc((size_t)T*BAT*HID*4);  // pre1 -> packed h1 (chunk)
  uint32_t* xp     = (uint32_t*)alloc((size_t)T*BAT*INF*4);  // packed x (chunk)
  float*    WcombF = (float*)   alloc((size_t)HID*INF*4);
  uint16_t* Wc_hi  = (uint16_t*)alloc((size_t)HID*INF*2);
  uint16_t* Wc_lo  = (uint16_t*)alloc((size_t)HID*INF*2);
  uint16_t* Wih1_hi= (uint16_t*)alloc((size_t)HID*HID*2);
  uint16_t* Wih1_lo= (uint16_t*)alloc((size_t)HID*HID*2);
  uint16_t* Whh0_hi= (uint16_t*)alloc((size_t)HID*HID*2);
  uint16_t* Whh0_lo= (uint16_t*)alloc((size_t)HID*HID*2);
  uint16_t* Whh1_hi= (uint16_t*)alloc((size_t)HID*HID*2);
  uint16_t* Whh1_lo= (uint16_t*)alloc((size_t)HID*HID*2);
  uint16_t* Wout_hi= (uint16_t*)alloc((size_t)INF*HID*2);
  uint16_t* Wout_lo= (uint16_t*)alloc((size_t)INF*HID*2);
  float*    bcomb  = (float*)   alloc((size_t)HID*4);
  uint32_t* h0s    = (uint32_t*)alloc((size_t)BAT*HID*4);
  uint32_t* h1s    = (uint32_t*)alloc((size_t)BAT*HID*4);
  uint32_t* ctr    = (uint32_t*)alloc(1024);

  // ---- prep ----
  wcomb_kernel<<<HID/16, 256, 0, stream>>>(W_ih, W_in, WcombF);
  bcomb_kernel<<<HID, 256, 0, stream>>>(W_ih, b_in, b_ih, bcomb);
  split_w<<<(HID*INF+255)/256, 256, 0, stream>>>(WcombF, Wc_hi, Wc_lo, HID*INF);
  split_w<<<(HID*HID+255)/256, 256, 0, stream>>>(W_ih + (size_t)HID*HID, Wih1_hi, Wih1_lo, HID*HID);
  split_w<<<(HID*HID+255)/256, 256, 0, stream>>>(W_hh, Whh0_hi, Whh0_lo, HID*HID);
  split_w<<<(HID*HID+255)/256, 256, 0, stream>>>(W_hh + (size_t)HID*HID, Whh1_hi, Whh1_lo, HID*HID);
  split_w<<<(INF*HID+255)/256, 256, 0, stream>>>(W_out, Wout_hi, Wout_lo, INF*HID);

  // ---- chunked pipeline ----
  for (int c = 0; c < nchunk; ++c){
    const float* xc = x + (size_t)c*T*BAT*INF;
    pack_x<<<T*BAT*INF/256, 256, 0, stream>>>(xc, xp, T*BAT*INF);
    // pre0 chunk = xp @ Wcomb^T + bcomb
    gemm_split<<<dim3(T*64/128, HID/128), 256, 0, stream>>>(xp, Wc_hi, Wc_lo, bcomb, buf0, HID, INF);
    // wavefront scan over the chunk (both layers + pre1 fused)
    hipMemsetAsync(ctr, 0, 1024, stream);
    rnn_persist<<<NWG, 256, 0, stream>>>(
        buf0, buf1, Whh0_hi, Whh0_lo, Wih1_hi, Wih1_lo, Whh1_hi, Whh1_lo,
        b_hh, b_ih + HID, b_hh + HID, h0s, h1s, ctr, T, (c == 0) ? 1 : 0);
    // out chunk = h1chunk @ Wout^T + b_out
    gemm_split<<<dim3(T*64/128, INF/128), 256, 0, stream>>>((const uint32_t*)buf1, Wout_hi, Wout_lo,
                                                            b_out, out + (size_t)c*T*BAT*INF, INF, HID);
  }
  extract_hidden<<<(2*BAT*HID)/256, 256, 0, stream>>>(h0s, h1s, out);
}

// Round 7
// 7758.263 us; speedup vs baseline: 1.4337x; 1.4337x over previous
//
#include <hip/hip_runtime.h>
#include <stdint.h>

#define SEQ 512
#define BAT 64
#define INF 256     // input features
#define HID 1024
#define SB  (SEQ*BAT)   // 32768 rows
#define G_WGS 64            // WGs per pipeline group
#define NWG (3*G_WGS)       // 192 persistent WGs

typedef __attribute__((ext_vector_type(8))) short short8;
typedef __attribute__((ext_vector_type(4))) float f32x4;

union Frag8 { uint32_t u[4]; short8 s; };

// ---------- numeric helpers: fp32 <-> (bf16 hi, bf16 lo) ----------
__device__ __forceinline__ uint32_t bf16hi_rne(uint32_t u){
  return (u + 0x7FFFu + ((u >> 16) & 1u)) & 0xFFFF0000u;
}
__device__ __forceinline__ uint32_t pack_split(float v){
  uint32_t hi = bf16hi_rne(__float_as_uint(v));
  float r = v - __uint_as_float(hi);
  uint32_t lo = bf16hi_rne(__float_as_uint(r)) >> 16;
  return hi | lo;                              // (hi16<<16) | lo16
}
__device__ __forceinline__ void unpack_pair(uint32_t u0, uint32_t u1,
                                            uint32_t& h, uint32_t& l){
  h = __builtin_amdgcn_perm(u1, u0, 0x07060302u);  // {u0.b2,u0.b3,u1.b2,u1.b3}
  l = __builtin_amdgcn_perm(u1, u0, 0x05040100u);  // {u0.b0,u0.b1,u1.b0,u1.b1}
}
__device__ __forceinline__ void gl16(const void* g, void* l){
  __builtin_amdgcn_global_load_lds(
      (const __attribute__((address_space(1))) void*)g,
      (__attribute__((address_space(3))) void*)l, 16, 0, 0);
}

// ---------- agent-scope atomics (flags + cross-WG visible writes) ----------
__device__ __forceinline__ void astore32(uint32_t* p, uint32_t v){
  __hip_atomic_store(p, v, __ATOMIC_RELAXED, __HIP_MEMORY_SCOPE_AGENT);
}
__device__ __forceinline__ void waitctr(uint32_t* c, uint32_t tgt){
  unsigned spins = 0;
  while (__hip_atomic_load(c, __ATOMIC_RELAXED, __HIP_MEMORY_SCOPE_AGENT) < tgt){
    __builtin_amdgcn_s_sleep(1);
    if (++spins > (1u << 22)) break;   // failsafe: no hang
  }
}

// ---------- prep kernels ----------
__global__ __launch_bounds__(256) void wcomb_kernel(const float* __restrict__ A,
                                                    const float* __restrict__ B,
                                                    float* __restrict__ C){
  __shared__ float As[16][64];
  __shared__ float Bs[64][256];
  const int tid = threadIdx.x;
  const int g0 = blockIdx.x * 16;
  float acc[16];
#pragma unroll
  for (int g = 0; g < 16; ++g) acc[g] = 0.f;
  for (int h0 = 0; h0 < HID; h0 += 64){
    __syncthreads();
#pragma unroll
    for (int j = 0; j < 4; ++j){
      int c = j*256 + tid;
      As[c >> 6][c & 63] = A[(size_t)(g0 + (c >> 6))*HID + h0 + (c & 63)];
    }
#pragma unroll
    for (int j = 0; j < 64; ++j) Bs[j][tid] = B[(size_t)(h0 + j)*INF + tid];
    __syncthreads();
#pragma unroll
    for (int hh = 0; hh < 64; hh += 4){
      float b0 = Bs[hh][tid], b1 = Bs[hh+1][tid], b2 = Bs[hh+2][tid], b3 = Bs[hh+3][tid];
#pragma unroll
      for (int g = 0; g < 16; ++g){
        const float4 a = *(const float4*)&As[g][hh];
        acc[g] += a.x*b0 + a.y*b1 + a.z*b2 + a.w*b3;
      }
    }
  }
#pragma unroll
  for (int g = 0; g < 16; ++g) C[(size_t)(g0 + g)*INF + tid] = acc[g];
}

__global__ __launch_bounds__(256) void bcomb_kernel(const float* __restrict__ Wih0,
                                                    const float* __restrict__ bin,
                                                    const float* __restrict__ bih0,
                                                    float* __restrict__ bcomb){
  __shared__ float r[4];
  const int g = blockIdx.x, tid = threadIdx.x;
  float s = 0.f;
  for (int h = tid; h < HID; h += 256) s += Wih0[(size_t)g*HID + h] * bin[h];
  for (int o = 32; o > 0; o >>= 1) s += __shfl_down(s, o, 64);
  if ((tid & 63) == 0) r[tid >> 6] = s;
  __syncthreads();
  if (tid == 0) bcomb[g] = bih0[g] + r[0] + r[1] + r[2] + r[3];
}

__global__ void split_w(const float* __restrict__ in, uint16_t* __restrict__ hi,
                        uint16_t* __restrict__ lo, int n){
  int i = blockIdx.x*256 + threadIdx.x;
  if (i < n){
    float v = in[i];
    uint32_t h = bf16hi_rne(__float_as_uint(v));
    float r = v - __uint_as_float(h);
    hi[i] = (uint16_t)(h >> 16);
    lo[i] = (uint16_t)(bf16hi_rne(__float_as_uint(r)) >> 16);
  }
}

__global__ void pack_x(const float* __restrict__ in, uint32_t* __restrict__ out, int n){
  int i = blockIdx.x*256 + threadIdx.x;
  if (i < n) out[i] = pack_split(in[i]);
}

// ---------- batched split GEMM (pre0 / out): C = unpack(A) @ (Whi+Wlo)^T + bias ----------
__global__ __launch_bounds__(256) void gemm_split(
    const uint32_t* __restrict__ A, const uint16_t* __restrict__ Whi,
    const uint16_t* __restrict__ Wlo, const float* __restrict__ bias,
    float* __restrict__ C, int N, int K)
{
  __shared__ uint32_t Al[128*32];
  __shared__ uint16_t Wh[128*32];
  __shared__ uint16_t Wl[128*32];
  const int tid  = threadIdx.x;
  const int lane = tid & 63;
  const int w    = tid >> 6;
  const int wm   = w >> 1, wn = w & 1;
  const int lr   = lane & 15, kg = lane >> 4;
  const int bm   = blockIdx.x, bn = blockIdx.y;

  const uint32_t* Ag  = A   + (size_t)bm*128*K;
  const uint16_t* Whg = Whi + (size_t)bn*128*K;
  const uint16_t* Wlg = Wlo + (size_t)bn*128*K;

  f32x4 acc[4][4];
#pragma unroll
  for (int i = 0; i < 4; ++i)
#pragma unroll
    for (int j = 0; j < 4; ++j) acc[i][j] = (f32x4){0.f,0.f,0.f,0.f};

  for (int ks = 0; ks < K; ks += 32){
    __syncthreads();
#pragma unroll
    for (int j = 0; j < 4; ++j){
      int c = j*256 + tid;
      int row = c >> 3, kc = c & 7;
      int kcs = kc ^ ((row & 3) << 1);
      gl16(Ag + (size_t)row*K + ks + kcs*4, (char*)Al + c*16);
    }
#pragma unroll
    for (int j = 0; j < 2; ++j){
      int c = j*256 + tid;
      int row = c >> 2, kc = c & 3;
      int kcs = kc ^ (row & 3);
      gl16(Whg + (size_t)row*K + ks + kcs*8, (char*)Wh + c*16);
      gl16(Wlg + (size_t)row*K + ks + kcs*8, (char*)Wl + c*16);
    }
    __syncthreads();

    short8 ah[4], al[4];
#pragma unroll
    for (int mt = 0; mt < 4; ++mt){
      int row = wm*64 + mt*16 + lr;
      int c2  = kg ^ (row & 3);
      const uint32_t* p = &Al[row*32 + c2*8];
      uint4 a0 = *(const uint4*)p;
      uint4 a1 = *(const uint4*)(p + 4);
      Frag8 fh, fl;
      unpack_pair(a0.x, a0.y, fh.u[0], fl.u[0]);
      unpack_pair(a0.z, a0.w, fh.u[1], fl.u[1]);
      unpack_pair(a1.x, a1.y, fh.u[2], fl.u[2]);
      unpack_pair(a1.z, a1.w, fh.u[3], fl.u[3]);
      ah[mt] = fh.s; al[mt] = fl.s;
    }
#pragma unroll
    for (int nt = 0; nt < 4; ++nt){
      int row = wn*64 + nt*16 + lr;
      int kc  = kg ^ (row & 3);
      short8 whf = *(const short8*)&Wh[row*32 + kc*8];
      short8 wlf = *(const short8*)&Wl[row*32 + kc*8];
#pragma unroll
      for (int mt = 0; mt < 4; ++mt){
        acc[mt][nt] = __builtin_amdgcn_mfma_f32_16x16x32_bf16(ah[mt], whf, acc[mt][nt], 0,0,0);
        acc[mt][nt] = __builtin_amdgcn_mfma_f32_16x16x32_bf16(al[mt], whf, acc[mt][nt], 0,0,0);
        acc[mt][nt] = __builtin_amdgcn_mfma_f32_16x16x32_bf16(ah[mt], wlf, acc[mt][nt], 0,0,0);
      }
    }
  }
#pragma unroll
  for (int nt = 0; nt < 4; ++nt){
    int col = bn*128 + wn*64 + nt*16 + lr;
    float bv = bias[col];
#pragma unroll
    for (int mt = 0; mt < 4; ++mt){
#pragma unroll
      for (int r = 0; r < 4; ++r){
        int rowg = bm*128 + wm*64 + mt*16 + kg*4 + r;
        C[(size_t)rowg*N + col] = acc[mt][nt][r] + bv;
      }
    }
  }
}

// ---------- persistent wavefront scan: plain pipelined loads, write-once buffers ----------
// 192 WGs x 256 thr (4 waves). group = wg/64: 0 = L0 recurrence (t=r),
// 1 = Wih1*h0 (t=r-1), 2 = L1 recurrence (t=r-2).
// sub = wg%64: rh = sub>>5 (32-row half), ci = sub&31 (32-col slice).
// Wave (mt=w>>1, ntw=w&1) owns a 16x16 out tile, full K=1024, 4 acc chains.
// W slice staged once into LDS in FRAGMENT-LINEAR order (lane-consecutive
// 16B chunks -> zero bank conflicts). Data reads are PLAIN loads (L1-cached,
// compiler-pipelined); cross-WG visible writes are sc1; flags sc1 counters.
__global__ __launch_bounds__(256, 1) void rnn_persist(
    const float* __restrict__ pre0, uint32_t* __restrict__ h0seq,
    uint32_t* __restrict__ pre1, uint32_t* __restrict__ h1seq,
    const uint16_t* __restrict__ Whh0h, const uint16_t* __restrict__ Whh0l,
    const uint16_t* __restrict__ Wih1h, const uint16_t* __restrict__ Wih1l,
    const uint16_t* __restrict__ Whh1h, const uint16_t* __restrict__ Whh1l,
    const float* __restrict__ bhh0, const float* __restrict__ bih1,
    const float* __restrict__ bhh1,
    uint32_t* h0s, uint32_t* h1s,
    uint32_t* ctr, int T, int first)
{
  __shared__ short WhF[32768];   // 64 KB, fragment-linear
  __shared__ short WlF[32768];   // 64 KB
  const int tid  = threadIdx.x;
  const int lane = tid & 63;
  const int w    = tid >> 6;                 // 0..3
  const int mt   = w >> 1, ntw = w & 1;
  const int lr   = lane & 15, kg = lane >> 4;
  const int wg   = blockIdx.x;
  const int group = wg / G_WGS;              // 0,1,2
  const int sub  = wg % G_WGS;
  const int rh   = sub >> 5;                 // 0..1 (rows 32*rh)
  const int ci   = sub & 31;                 // 0..31 (cols 32*ci)
  const int col0 = ci * 32;

  uint32_t* c0 = ctr;          // G0 step counter (64 per step)
  uint32_t* c1 = ctr + 64;     // G1
  uint32_t* c2 = ctr + 128;    // G2
  uint32_t* cmy = (group == 0) ? c0 : (group == 1) ? c1 : c2;

  const uint16_t* Whg = (group == 0) ? Whh0h : (group == 1) ? Wih1h : Whh1h;
  const uint16_t* Wlg = (group == 0) ? Whh0l : (group == 1) ? Wih1l : Whh1l;

  // ---- stage W slice into LDS once, fragment-linear:
  // chunk(col c, j) -> frag block (ntw=c>>4, ks=j>>2), lane=(j&3)*16+(c&15)
#pragma unroll
  for (int it = 0; it < 16; ++it){
    int lin = it*256 + tid;          // 0..4095
    int c = lin >> 7, j = lin & 127;
    int dst = (((c >> 4)*32 + (j >> 2))*64 + (j & 3)*16 + (c & 15))*8;
    *(uint4*)&WhF[dst] = *(const uint4*)&Whg[(size_t)(col0 + c)*HID + j*8];
    *(uint4*)&WlF[dst] = *(const uint4*)&Wlg[(size_t)(col0 + c)*HID + j*8];
  }
  __syncthreads();

  const int fragbase = ntw*32*512 + lane*8;   // + ks*512 shorts

  const int R = T + 2;
  for (int r = 0; r < R; ++r){
    const int t = r - group;
    const bool valid = (t >= 0 && t < T);

    // ---- dependency waits (relaxed polls on sc1 counters) ----
    if (tid == 0){
      if (group == 0){
        if (valid && t > 0) waitctr(c0, 64u*(unsigned)t);
      } else if (group == 1){
        if (valid) waitctr(c0, 64u*(unsigned)(t+1));
      } else {
        if (valid){
          waitctr(c1, 64u*(unsigned)(t+1));
          if (t > 0) waitctr(c2, 64u*(unsigned)t);
        }
      }
    }
    __syncthreads();
    asm volatile("" ::: "memory");

    if (valid){
      // A = packed h (write-once buffers; safe to read with plain loads)
      const uint32_t* Ap;
      if (group == 0)
        Ap = (t == 0) ? (first ? (const uint32_t*)0 : h0s)
                      : h0seq + (size_t)(t-1)*(BAT*HID);
      else if (group == 1)
        Ap = h0seq + (size_t)t*(BAT*HID);
      else
        Ap = (t == 0) ? (first ? (const uint32_t*)0 : h1s)
                      : h1seq + (size_t)(t-1)*(BAT*HID);

      f32x4 acc[4];
#pragma unroll
      for (int i = 0; i < 4; ++i) acc[i] = (f32x4){0.f,0.f,0.f,0.f};

      if (Ap){
        const int arow = rh*32 + mt*16 + lr;
        const uint4* Ab = (const uint4*)(Ap + (size_t)arow*HID) + kg*2;
#pragma unroll
        for (int ks = 0; ks < 32; ++ks){
          uint4 a0 = Ab[ks*8];
          uint4 a1 = Ab[ks*8 + 1];
          Frag8 fh, fl;
          unpack_pair(a0.x, a0.y, fh.u[0], fl.u[0]);
          unpack_pair(a0.z, a0.w, fh.u[1], fl.u[1]);
          unpack_pair(a1.x, a1.y, fh.u[2], fl.u[2]);
          unpack_pair(a1.z, a1.w, fh.u[3], fl.u[3]);
          short8 whf = *(const short8*)&WhF[fragbase + ks*512];
          short8 wlf = *(const short8*)&WlF[fragbase + ks*512];
          acc[ks & 3] = __builtin_amdgcn_mfma_f32_16x16x32_bf16(fh.s, whf, acc[ks & 3], 0,0,0);
          acc[ks & 3] = __builtin_amdgcn_mfma_f32_16x16x32_bf16(fl.s, whf, acc[ks & 3], 0,0,0);
          acc[ks & 3] = __builtin_amdgcn_mfma_f32_16x16x32_bf16(fh.s, wlf, acc[ks & 3], 0,0,0);
        }
      }
      f32x4 s = (acc[0] + acc[1]) + (acc[2] + acc[3]);

      // ---- epilogue: D col = ntw*16+lr, row = mt*16+kg*4+q ----
      const int col = col0 + ntw*16 + lr;
      const int rowb = rh*32 + mt*16 + kg*4;
      if (group == 0){
        const float bv = bhh0[col];
#pragma unroll
        for (int q = 0; q < 4; ++q){
          const size_t idx = (size_t)t*(BAT*HID) + (size_t)(rowb + q)*HID + col;
          float v = tanhf(s[q] + pre0[idx] + bv);
          uint32_t pk = pack_split(v);
          astore32(h0seq + idx, pk);
          if (t == T-1) astore32(h0s + (size_t)(rowb + q)*HID + col, pk);
        }
      } else if (group == 1){
        const float bv = bih1[col] + bhh1[col];
#pragma unroll
        for (int q = 0; q < 4; ++q){
          const size_t idx = (size_t)t*(BAT*HID) + (size_t)(rowb + q)*HID + col;
          astore32(pre1 + idx, __float_as_uint(s[q] + bv));
        }
      } else {
#pragma unroll
        for (int q = 0; q < 4; ++q){
          const size_t idx = (size_t)t*(BAT*HID) + (size_t)(rowb + q)*HID + col;
          float pv = __uint_as_float(pre1[idx]);   // plain read (write-once)
          float v = tanhf(s[q] + pv);
          uint32_t pk = pack_split(v);
          astore32(h1seq + idx, pk);
          if (t == T-1) astore32(h1s + (size_t)(rowb + q)*HID + col, pk);
        }
      }
    }

    // drain sc1 stores to the coherence point, then signal
    asm volatile("s_waitcnt vmcnt(0) lgkmcnt(0)" ::: "memory");
    __syncthreads();
    if (tid == 0 && valid)
      __hip_atomic_fetch_add(cmy, 1u, __ATOMIC_RELAXED, __HIP_MEMORY_SCOPE_AGENT);
  }
}

// ---------- hidden output from carried states ----------
__global__ void extract_hidden(const uint32_t* __restrict__ h0s,
                               const uint32_t* __restrict__ h1s,
                               float* __restrict__ out){
  int i = blockIdx.x*256 + threadIdx.x;   // 0..131071
  uint32_t p = (i >> 16) ? h1s[i & 65535] : h0s[i & 65535];
  out[(size_t)SB*INF + i] = __uint_as_float(p & 0xFFFF0000u) + __uint_as_float(p << 16);
}

// ---------- host ----------
extern "C" void kernel_launch(void* const* d_in, const int* in_sizes, int n_in,
                              void* d_out, int out_size, void* d_ws, size_t ws_size,
                              hipStream_t stream)
{
  const float* x    = (const float*)d_in[0];
  const float* W_in = (const float*)d_in[1];
  const float* b_in = (const float*)d_in[2];
  const float* W_ih = (const float*)d_in[3];   // [2][H][H]
  const float* W_hh = (const float*)d_in[4];   // [2][H][H]
  const float* b_ih = (const float*)d_in[5];   // [2][H]
  const float* b_hh = (const float*)d_in[6];   // [2][H]
  const float* W_out= (const float*)d_in[7];   // [I][H]
  const float* b_out= (const float*)d_in[8];
  float* out = (float*)d_out;
  (void)in_sizes; (void)n_in; (void)out_size;

  // ---- choose chunk length T to fit ws_size ----
  // fixed ~16.3 MB; per-T = pre0+h0+pre1+h1 (256 KB each) + xp (64 KB)
  const size_t fixedB = 16257024 + 4096;
  const size_t perT   = 1114112;
  int T = 512;
  while (T > 2 && fixedB + (size_t)T*perT + 65536 > ws_size) T >>= 1;
  const int nchunk = SEQ / T;

  char* ws = (char*)d_ws;
  size_t off = 0;
  auto alloc = [&](size_t bytes)->void*{
    void* p = ws + off; off += (bytes + 255) & ~(size_t)255; return p;
  };
  float*    pre0s  = (float*)   alloc((size_t)T*BAT*HID*4);
  uint32_t* h0seq  = (uint32_t*)alloc((size_t)T*BAT*HID*4);
  uint32_t* pre1s  = (uint32_t*)alloc((size_t)T*BAT*HID*4);
  uint32_t* h1seq  = (uint32_t*)alloc((size_t)T*BAT*HID*4);
  uint32_t* xp     = (uint32_t*)alloc((size_t)T*BAT*INF*4);
  float*    WcombF = (float*)   alloc((size_t)HID*INF*4);
  uint16_t* Wc_hi  = (uint16_t*)alloc((size_t)HID*INF*2);
  uint16_t* Wc_lo  = (uint16_t*)alloc((size_t)HID*INF*2);
  uint16_t* Wih1_hi= (uint16_t*)alloc((size_t)HID*HID*2);
  uint16_t* Wih1_lo= (uint16_t*)alloc((size_t)HID*HID*2);
  uint16_t* Whh0_hi= (uint16_t*)alloc((size_t)HID*HID*2);
  uint16_t* Whh0_lo= (uint16_t*)alloc((size_t)HID*HID*2);
  uint16_t* Whh1_hi= (uint16_t*)alloc((size_t)HID*HID*2);
  uint16_t* Whh1_lo= (uint16_t*)alloc((size_t)HID*HID*2);
  uint16_t* Wout_hi= (uint16_t*)alloc((size_t)INF*HID*2);
  uint16_t* Wout_lo= (uint16_t*)alloc((size_t)INF*HID*2);
  float*    bcomb  = (float*)   alloc((size_t)HID*4);
  uint32_t* h0s    = (uint32_t*)alloc((size_t)BAT*HID*4);
  uint32_t* h1s    = (uint32_t*)alloc((size_t)BAT*HID*4);
  uint32_t* ctr    = (uint32_t*)alloc(1024);

  // ---- prep ----
  wcomb_kernel<<<HID/16, 256, 0, stream>>>(W_ih, W_in, WcombF);
  bcomb_kernel<<<HID, 256, 0, stream>>>(W_ih, b_in, b_ih, bcomb);
  split_w<<<(HID*INF+255)/256, 256, 0, stream>>>(WcombF, Wc_hi, Wc_lo, HID*INF);
  split_w<<<(HID*HID+255)/256, 256, 0, stream>>>(W_ih + (size_t)HID*HID, Wih1_hi, Wih1_lo, HID*HID);
  split_w<<<(HID*HID+255)/256, 256, 0, stream>>>(W_hh, Whh0_hi, Whh0_lo, HID*HID);
  split_w<<<(HID*HID+255)/256, 256, 0, stream>>>(W_hh + (size_t)HID*HID, Whh1_hi, Whh1_lo, HID*HID);
  split_w<<<(INF*HID+255)/256, 256, 0, stream>>>(W_out, Wout_hi, Wout_lo, INF*HID);

  // ---- chunked pipeline ----
  for (int c = 0; c < nchunk; ++c){
    const float* xc = x + (size_t)c*T*BAT*INF;
    pack_x<<<T*BAT*INF/256, 256, 0, stream>>>(xc, xp, T*BAT*INF);
    // pre0 chunk = xp @ Wcomb^T + bcomb
    gemm_split<<<dim3(T*64/128, HID/128), 256, 0, stream>>>(xp, Wc_hi, Wc_lo, bcomb, pre0s, HID, INF);
    // wavefront scan over the chunk (both layers + pre1 fused)
    hipMemsetAsync(ctr, 0, 1024, stream);
    rnn_persist<<<NWG, 256, 0, stream>>>(
        pre0s, h0seq, pre1s, h1seq,
        Whh0_hi, Whh0_lo, Wih1_hi, Wih1_lo, Whh1_hi, Whh1_lo,
        b_hh, b_ih + HID, b_hh + HID, h0s, h1s, ctr, T, (c == 0) ? 1 : 0);
    // out chunk = h1chunk @ Wout^T + b_out
    gemm_split<<<dim3(T*64/128, INF/128), 256, 0, stream>>>(h1seq, Wout_hi, Wout_lo,
                                                            b_out, out + (size_t)c*T*BAT*INF, INF, HID);
  }
  extract_hidden<<<(2*BAT*HID)/256, 256, 0, stream>>>(h0s, h1s, out);
}

// Round 10
// 5616.495 us; speedup vs baseline: 1.9805x; 1.3813x over previous
//
#include <hip/hip_runtime.h>
#include <stdint.h>

#define SEQ 512
#define BAT 64
#define INF 256     // input features
#define HID 1024
#define SB  (SEQ*BAT)   // 32768 rows
#define G_WGS 64            // WGs per pipeline group
#define NWG (3*G_WGS)       // 192 persistent WGs

typedef __attribute__((ext_vector_type(8))) short short8;
typedef __attribute__((ext_vector_type(4))) float f32x4;

union Frag8 { uint32_t u[4]; short8 s; };

// ---------- numeric helpers: fp32 <-> (bf16 hi, bf16 lo) ----------
__device__ __forceinline__ uint32_t bf16hi_rne(uint32_t u){
  return (u + 0x7FFFu + ((u >> 16) & 1u)) & 0xFFFF0000u;
}
__device__ __forceinline__ uint32_t pack_split(float v){
  uint32_t hi = bf16hi_rne(__float_as_uint(v));
  float r = v - __uint_as_float(hi);
  uint32_t lo = bf16hi_rne(__float_as_uint(r)) >> 16;
  return hi | lo;                              // (hi16<<16) | lo16
}
__device__ __forceinline__ void unpack_pair(uint32_t u0, uint32_t u1,
                                            uint32_t& h, uint32_t& l){
  h = __builtin_amdgcn_perm(u1, u0, 0x07060302u);  // {u0.b2,u0.b3,u1.b2,u1.b3}
  l = __builtin_amdgcn_perm(u1, u0, 0x05040100u);  // {u0.b0,u0.b1,u1.b0,u1.b1}
}
__device__ __forceinline__ void gl16(const void* g, void* l){
  __builtin_amdgcn_global_load_lds(
      (const __attribute__((address_space(1))) void*)g,
      (__attribute__((address_space(3))) void*)l, 16, 0, 0);
}

// ---------- agent-scope atomics (flags + cross-WG visible writes) ----------
__device__ __forceinline__ void astore32(uint32_t* p, uint32_t v){
  __hip_atomic_store(p, v, __ATOMIC_RELAXED, __HIP_MEMORY_SCOPE_AGENT);
}
__device__ __forceinline__ void waitctr(uint32_t* c, uint32_t tgt){
  unsigned spins = 0;
  while (__hip_atomic_load(c, __ATOMIC_RELAXED, __HIP_MEMORY_SCOPE_AGENT) < tgt){
    __builtin_amdgcn_s_sleep(1);
    if (++spins > (1u << 20)) break;   // failsafe: fail fast, never wedge
  }
}

// ---------- prep kernels ----------
__global__ __launch_bounds__(256) void wcomb_kernel(const float* __restrict__ A,
                                                    const float* __restrict__ B,
                                                    float* __restrict__ C){
  __shared__ float As[16][64];
  __shared__ float Bs[64][256];
  const int tid = threadIdx.x;
  const int g0 = blockIdx.x * 16;
  float acc[16];
#pragma unroll
  for (int g = 0; g < 16; ++g) acc[g] = 0.f;
  for (int h0 = 0; h0 < HID; h0 += 64){
    __syncthreads();
#pragma unroll
    for (int j = 0; j < 4; ++j){
      int c = j*256 + tid;
      As[c >> 6][c & 63] = A[(size_t)(g0 + (c >> 6))*HID + h0 + (c & 63)];
    }
#pragma unroll
    for (int j = 0; j < 64; ++j) Bs[j][tid] = B[(size_t)(h0 + j)*INF + tid];
    __syncthreads();
#pragma unroll
    for (int hh = 0; hh < 64; hh += 4){
      float b0 = Bs[hh][tid], b1 = Bs[hh+1][tid], b2 = Bs[hh+2][tid], b3 = Bs[hh+3][tid];
#pragma unroll
      for (int g = 0; g < 16; ++g){
        const float4 a = *(const float4*)&As[g][hh];
        acc[g] += a.x*b0 + a.y*b1 + a.z*b2 + a.w*b3;
      }
    }
  }
#pragma unroll
  for (int g = 0; g < 16; ++g) C[(size_t)(g0 + g)*INF + tid] = acc[g];
}

__global__ __launch_bounds__(256) void bcomb_kernel(const float* __restrict__ Wih0,
                                                    const float* __restrict__ bin,
                                                    const float* __restrict__ bih0,
                                                    float* __restrict__ bcomb){
  __shared__ float r[4];
  const int g = blockIdx.x, tid = threadIdx.x;
  float s = 0.f;
  for (int h = tid; h < HID; h += 256) s += Wih0[(size_t)g*HID + h] * bin[h];
  for (int o = 32; o > 0; o >>= 1) s += __shfl_down(s, o, 64);
  if ((tid & 63) == 0) r[tid >> 6] = s;
  __syncthreads();
  if (tid == 0) bcomb[g] = bih0[g] + r[0] + r[1] + r[2] + r[3];
}

__global__ void split_w(const float* __restrict__ in, uint16_t* __restrict__ hi,
                        uint16_t* __restrict__ lo, int n){
  int i = blockIdx.x*256 + threadIdx.x;
  if (i < n){
    float v = in[i];
    uint32_t h = bf16hi_rne(__float_as_uint(v));
    float r = v - __uint_as_float(h);
    hi[i] = (uint16_t)(h >> 16);
    lo[i] = (uint16_t)(bf16hi_rne(__float_as_uint(r)) >> 16);
  }
}

__global__ void pack_x(const float* __restrict__ in, uint32_t* __restrict__ out, int n){
  int i = blockIdx.x*256 + threadIdx.x;
  if (i < n) out[i] = pack_split(in[i]);
}

// ---------- batched split GEMM (pre0 / out): C = unpack(A) @ (Whi+Wlo)^T + bias ----------
__global__ __launch_bounds__(256) void gemm_split(
    const uint32_t* __restrict__ A, const uint16_t* __restrict__ Whi,
    const uint16_t* __restrict__ Wlo, const float* __restrict__ bias,
    float* __restrict__ C, int N, int K)
{
  __shared__ uint32_t Al[128*32];
  __shared__ uint16_t Wh[128*32];
  __shared__ uint16_t Wl[128*32];
  const int tid  = threadIdx.x;
  const int lane = tid & 63;
  const int w    = tid >> 6;
  const int wm   = w >> 1, wn = w & 1;
  const int lr   = lane & 15, kg = lane >> 4;
  const int bm   = blockIdx.x, bn = blockIdx.y;

  const uint32_t* Ag  = A   + (size_t)bm*128*K;
  const uint16_t* Whg = Whi + (size_t)bn*128*K;
  const uint16_t* Wlg = Wlo + (size_t)bn*128*K;

  f32x4 acc[4][4];
#pragma unroll
  for (int i = 0; i < 4; ++i)
#pragma unroll
    for (int j = 0; j < 4; ++j) acc[i][j] = (f32x4){0.f,0.f,0.f,0.f};

  for (int ks = 0; ks < K; ks += 32){
    __syncthreads();
#pragma unroll
    for (int j = 0; j < 4; ++j){
      int c = j*256 + tid;
      int row = c >> 3, kc = c & 7;
      int kcs = kc ^ ((row & 3) << 1);
      gl16(Ag + (size_t)row*K + ks + kcs*4, (char*)Al + c*16);
    }
#pragma unroll
    for (int j = 0; j < 2; ++j){
      int c = j*256 + tid;
      int row = c >> 2, kc = c & 3;
      int kcs = kc ^ (row & 3);
      gl16(Whg + (size_t)row*K + ks + kcs*8, (char*)Wh + c*16);
      gl16(Wlg + (size_t)row*K + ks + kcs*8, (char*)Wl + c*16);
    }
    __syncthreads();

    short8 ah[4], al[4];
#pragma unroll
    for (int mt = 0; mt < 4; ++mt){
      int row = wm*64 + mt*16 + lr;
      int c2  = kg ^ (row & 3);
      const uint32_t* p = &Al[row*32 + c2*8];
      uint4 a0 = *(const uint4*)p;
      uint4 a1 = *(const uint4*)(p + 4);
      Frag8 fh, fl;
      unpack_pair(a0.x, a0.y, fh.u[0], fl.u[0]);
      unpack_pair(a0.z, a0.w, fh.u[1], fl.u[1]);
      unpack_pair(a1.x, a1.y, fh.u[2], fl.u[2]);
      unpack_pair(a1.z, a1.w, fh.u[3], fl.u[3]);
      ah[mt] = fh.s; al[mt] = fl.s;
    }
#pragma unroll
    for (int nt = 0; nt < 4; ++nt){
      int row = wn*64 + nt*16 + lr;
      int kc  = kg ^ (row & 3);
      short8 whf = *(const short8*)&Wh[row*32 + kc*8];
      short8 wlf = *(const short8*)&Wl[row*32 + kc*8];
#pragma unroll
      for (int mt = 0; mt < 4; ++mt){
        acc[mt][nt] = __builtin_amdgcn_mfma_f32_16x16x32_bf16(ah[mt], whf, acc[mt][nt], 0,0,0);
        acc[mt][nt] = __builtin_amdgcn_mfma_f32_16x16x32_bf16(al[mt], whf, acc[mt][nt], 0,0,0);
        acc[mt][nt] = __builtin_amdgcn_mfma_f32_16x16x32_bf16(ah[mt], wlf, acc[mt][nt], 0,0,0);
      }
    }
  }
#pragma unroll
  for (int nt = 0; nt < 4; ++nt){
    int col = bn*128 + wn*64 + nt*16 + lr;
    float bv = bias[col];
#pragma unroll
    for (int mt = 0; mt < 4; ++mt){
#pragma unroll
      for (int r = 0; r < 4; ++r){
        int rowg = bm*128 + wm*64 + mt*16 + kg*4 + r;
        C[(size_t)rowg*N + col] = acc[mt][nt][r] + bv;
      }
    }
  }
}

// ---------- persistent wavefront scan: DMA-staged A, weights in LDS ----------
// 192 WGs x 256 thr (4 waves). group = wg/64: 0 = L0 recurrence (t=r),
// 1 = Wih1*h0 (t=r-1), 2 = L1 recurrence (t=r-2).
// sub = wg%64: rh = sub>>5 (32-row half), ci = sub&31 (32-col slice).
// Wave (mt=w>>1, ntw=w&1) owns a 16x16 out tile, full K=1024.
// W slice in LDS fragment-linear (128 KB). A (packed h, 128 KB/round) is
// DMA-staged via global_load_lds in 8 double-buffered 16 KB chunks with
// counted vmcnt + raw s_barrier (no full drains inside the pipeline).
// A LDS layout: [row][pos16B], pos swizzled by p3(row)=((row&3)<<1)|((row>>2)&1)
// (pre-swizzled global source, linear DMA dest, swizzled ds_read).
__global__ __launch_bounds__(256, 1) void rnn_persist(
    const float* __restrict__ pre0, uint32_t* __restrict__ h0seq,
    uint32_t* __restrict__ pre1, uint32_t* __restrict__ h1seq,
    const uint16_t* __restrict__ Whh0h, const uint16_t* __restrict__ Whh0l,
    const uint16_t* __restrict__ Wih1h, const uint16_t* __restrict__ Wih1l,
    const uint16_t* __restrict__ Whh1h, const uint16_t* __restrict__ Whh1l,
    const float* __restrict__ bhh0, const float* __restrict__ bih1,
    const float* __restrict__ bhh1,
    uint32_t* h0s, uint32_t* h1s,
    uint32_t* ctr, int T, int first)
{
  __shared__ short WhF[32768];        // 64 KB, fragment-linear
  __shared__ short WlF[32768];        // 64 KB
  __shared__ uint32_t Abuf[2][4096];  // 2 x 16 KB A chunks
  const int tid  = threadIdx.x;
  const int lane = tid & 63;
  const int w    = tid >> 6;                 // 0..3
  const int mt   = w >> 1, ntw = w & 1;
  const int lr   = lane & 15, kg = lane >> 4;
  const int wg   = blockIdx.x;
  const int group = wg / G_WGS;              // 0,1,2
  const int sub  = wg % G_WGS;
  const int rh   = sub >> 5;                 // 0..1 (rows 32*rh)
  const int ci   = sub & 31;                 // 0..31 (cols 32*ci)
  const int col0 = ci * 32;

  uint32_t* c0 = ctr;          // G0 step counter (64 per step)
  uint32_t* c1 = ctr + 64;     // G1
  uint32_t* c2 = ctr + 128;    // G2
  uint32_t* cmy = (group == 0) ? c0 : (group == 1) ? c1 : c2;

  const uint16_t* Whg = (group == 0) ? Whh0h : (group == 1) ? Wih1h : Whh1h;
  const uint16_t* Wlg = (group == 0) ? Whh0l : (group == 1) ? Wih1l : Whh1l;

  // ---- stage W slice into LDS once, fragment-linear ----
#pragma unroll
  for (int it = 0; it < 16; ++it){
    int lin = it*256 + tid;          // 0..4095
    int c = lin >> 7, j = lin & 127;
    int dst = (((c >> 4)*32 + (j >> 2))*64 + (j & 3)*16 + (c & 15))*8;
    *(uint4*)&WhF[dst] = *(const uint4*)&Whg[(size_t)(col0 + c)*HID + j*8];
    *(uint4*)&WlF[dst] = *(const uint4*)&Wlg[(size_t)(col0 + c)*HID + j*8];
  }
  __syncthreads();

  const int fragbase = ntw*16384 + lane*8;       // shorts; + ks*512
  const int arow = mt*16 + lr;                   // local A row this lane reads
  const int p3r  = ((arow & 3) << 1) | ((arow >> 2) & 1);
  const int abase_rd = arow * 128;               // u32 index of row base

  // staging lane constants: lane covers (rowpair + lane>>5, pos = lane&31)
  const int srow = lane >> 5;
  const int spos = lane & 31;

  const int col = col0 + ntw*16 + lr;
  const float bvg = (group == 0) ? bhh0[col]
                   : (group == 1) ? (bih1[col] + bhh1[col]) : 0.f;

  const int R = T + 2;
  for (int r = 0; r < R; ++r){
    const int t = r - group;
    const bool valid = (t >= 0 && t < T);

    // ---- dependency waits (relaxed polls on sc1 counters) ----
    if (tid == 0){
      if (group == 0){
        if (valid && t > 0) waitctr(c0, 64u*(unsigned)t);
      } else if (group == 1){
        if (valid) waitctr(c0, 64u*(unsigned)(t+1));
      } else {
        if (valid){
          waitctr(c1, 64u*(unsigned)(t+1));
          if (t > 0) waitctr(c2, 64u*(unsigned)t);
        }
      }
    }
    __syncthreads();
    asm volatile("" ::: "memory");

    if (valid){
      const uint32_t* Ap;
      if (group == 0)
        Ap = (t == 0) ? (first ? (const uint32_t*)0 : h0s)
                      : h0seq + (size_t)(t-1)*(BAT*HID);
      else if (group == 1)
        Ap = h0seq + (size_t)t*(BAT*HID);
      else
        Ap = (t == 0) ? (first ? (const uint32_t*)0 : h1s)
                      : h1seq + (size_t)(t-1)*(BAT*HID);

      // hoisted epilogue-input loads (overlap with DMA pipeline)
      const int rowb = rh*32 + mt*16 + kg*4;
      const size_t idx0 = (size_t)t*(BAT*HID) + (size_t)rowb*HID + col;
      float pv[4] = {0.f,0.f,0.f,0.f};
      if (group == 0){
#pragma unroll
        for (int q = 0; q < 4; ++q) pv[q] = pre0[idx0 + (size_t)q*HID];
      } else if (group == 2){
#pragma unroll
        for (int q = 0; q < 4; ++q) pv[q] = __uint_as_float(pre1[idx0 + (size_t)q*HID]);
      }

      f32x4 acc[4];
#pragma unroll
      for (int i = 0; i < 4; ++i) acc[i] = (f32x4){0.f,0.f,0.f,0.f};

      if (Ap){
        // stage one 16 KB chunk (128 K-values x 32 rows): 4 gl16 per lane
        auto STAGE = [&](int kc, int sl){
#pragma unroll
          for (int j = 0; j < 4; ++j){
            const int row_l = w*8 + j*2 + srow;
            const int p3 = ((row_l & 3) << 1) | ((row_l >> 2) & 1);
            const int pg = spos ^ p3;
            const uint32_t* src = Ap + (size_t)(rh*32 + row_l)*HID + kc*128 + pg*4;
            gl16(src, (char*)&Abuf[sl][(w*8 + j*2)*128] + lane*16);
          }
        };

        STAGE(0, 0);
#pragma unroll
        for (int kc = 0; kc < 8; ++kc){
          if (kc < 7){
            STAGE(kc+1, (kc+1) & 1);
            asm volatile("s_waitcnt vmcnt(4)" ::: "memory");
          } else {
            asm volatile("s_waitcnt vmcnt(0)" ::: "memory");
          }
          __builtin_amdgcn_sched_barrier(0);
          __builtin_amdgcn_s_barrier();
          asm volatile("" ::: "memory");
          const uint32_t* Ab = &Abuf[kc & 1][abase_rd];
#pragma unroll
          for (int kq = 0; kq < 4; ++kq){
            const int s0 = ((kq*4 + kg)*2) ^ p3r;
            uint4 a0 = *(const uint4*)&Ab[s0*4];
            uint4 a1 = *(const uint4*)&Ab[(s0^1)*4];
            Frag8 fh, fl;
            unpack_pair(a0.x, a0.y, fh.u[0], fl.u[0]);
            unpack_pair(a0.z, a0.w, fh.u[1], fl.u[1]);
            unpack_pair(a1.x, a1.y, fh.u[2], fl.u[2]);
            unpack_pair(a1.z, a1.w, fh.u[3], fl.u[3]);
            const int ks = kc*4 + kq;
            short8 whf = *(const short8*)&WhF[fragbase + ks*512];
            short8 wlf = *(const short8*)&WlF[fragbase + ks*512];
            acc[kq] = __builtin_amdgcn_mfma_f32_16x16x32_bf16(fh.s, whf, acc[kq], 0,0,0);
            acc[kq] = __builtin_amdgcn_mfma_f32_16x16x32_bf16(fl.s, whf, acc[kq], 0,0,0);
            acc[kq] = __builtin_amdgcn_mfma_f32_16x16x32_bf16(fh.s, wlf, acc[kq], 0,0,0);
          }
          asm volatile("" ::: "memory");
          __builtin_amdgcn_s_barrier();
        }
      }
      f32x4 s = (acc[0] + acc[1]) + (acc[2] + acc[3]);

      // ---- epilogue ----
      const int rowb2 = rh*32 + mt*16 + kg*4;
      const size_t idxe = (size_t)t*(BAT*HID) + (size_t)rowb2*HID + col;
      if (group == 0){
#pragma unroll
        for (int q = 0; q < 4; ++q){
          const size_t idx = idxe + (size_t)q*HID;
          float v = tanhf(s[q] + pv[q] + bvg);
          uint32_t pk = pack_split(v);
          astore32(h0seq + idx, pk);
          if (t == T-1) astore32(h0s + (size_t)(rowb2 + q)*HID + col, pk);
        }
      } else if (group == 1){
#pragma unroll
        for (int q = 0; q < 4; ++q){
          const size_t idx = idxe + (size_t)q*HID;
          astore32(pre1 + idx, __float_as_uint(s[q] + bvg));
        }
      } else {
#pragma unroll
        for (int q = 0; q < 4; ++q){
          const size_t idx = idxe + (size_t)q*HID;
          float v = tanhf(s[q] + pv[q]);
          uint32_t pk = pack_split(v);
          astore32(h1seq + idx, pk);
          if (t == T-1) astore32(h1s + (size_t)(rowb2 + q)*HID + col, pk);
        }
      }
    }

    // drain sc1 stores to the coherence point, then signal
    asm volatile("s_waitcnt vmcnt(0) lgkmcnt(0)" ::: "memory");
    __syncthreads();
    if (tid == 0 && valid)
      __hip_atomic_fetch_add(cmy, 1u, __ATOMIC_RELAXED, __HIP_MEMORY_SCOPE_AGENT);
  }
}

// ---------- hidden output from carried states ----------
__global__ void extract_hidden(const uint32_t* __restrict__ h0s,
                               const uint32_t* __restrict__ h1s,
                               float* __restrict__ out){
  int i = blockIdx.x*256 + threadIdx.x;   // 0..131071
  uint32_t p = (i >> 16) ? h1s[i & 65535] : h0s[i & 65535];
  out[(size_t)SB*INF + i] = __uint_as_float(p & 0xFFFF0000u) + __uint_as_float(p << 16);
}

// ---------- host ----------
extern "C" void kernel_launch(void* const* d_in, const int* in_sizes, int n_in,
                              void* d_out, int out_size, void* d_ws, size_t ws_size,
                              hipStream_t stream)
{
  const float* x    = (const float*)d_in[0];
  const float* W_in = (const float*)d_in[1];
  const float* b_in = (const float*)d_in[2];
  const float* W_ih = (const float*)d_in[3];   // [2][H][H]
  const float* W_hh = (const float*)d_in[4];   // [2][H][H]
  const float* b_ih = (const float*)d_in[5];   // [2][H]
  const float* b_hh = (const float*)d_in[6];   // [2][H]
  const float* W_out= (const float*)d_in[7];   // [I][H]
  const float* b_out= (const float*)d_in[8];
  float* out = (float*)d_out;
  (void)in_sizes; (void)n_in; (void)out_size;

  // ---- choose chunk length T to fit ws_size ----
  // fixed ~16.3 MB; per-T = pre0+h0+pre1+h1 (256 KB each) + xp (64 KB)
  const size_t fixedB = 16257024 + 4096;
  const size_t perT   = 1114112;
  int T = 512;
  while (T > 2 && fixedB + (size_t)T*perT + 65536 > ws_size) T >>= 1;
  const int nchunk = SEQ / T;

  char* ws = (char*)d_ws;
  size_t off = 0;
  auto alloc = [&](size_t bytes)->void*{
    void* p = ws + off; off += (bytes + 255) & ~(size_t)255; return p;
  };
  float*    pre0s  = (float*)   alloc((size_t)T*BAT*HID*4);
  uint32_t* h0seq  = (uint32_t*)alloc((size_t)T*BAT*HID*4);
  uint32_t* pre1s  = (uint32_t*)alloc((size_t)T*BAT*HID*4);
  uint32_t* h1seq  = (uint32_t*)alloc((size_t)T*BAT*HID*4);
  uint32_t* xp     = (uint32_t*)alloc((size_t)T*BAT*INF*4);
  float*    WcombF = (float*)   alloc((size_t)HID*INF*4);
  uint16_t* Wc_hi  = (uint16_t*)alloc((size_t)HID*INF*2);
  uint16_t* Wc_lo  = (uint16_t*)alloc((size_t)HID*INF*2);
  uint16_t* Wih1_hi= (uint16_t*)alloc((size_t)HID*HID*2);
  uint16_t* Wih1_lo= (uint16_t*)alloc((size_t)HID*HID*2);
  uint16_t* Whh0_hi= (uint16_t*)alloc((size_t)HID*HID*2);
  uint16_t* Whh0_lo= (uint16_t*)alloc((size_t)HID*HID*2);
  uint16_t* Whh1_hi= (uint16_t*)alloc((size_t)HID*HID*2);
  uint16_t* Whh1_lo= (uint16_t*)alloc((size_t)HID*HID*2);
  uint16_t* Wout_hi= (uint16_t*)alloc((size_t)INF*HID*2);
  uint16_t* Wout_lo= (uint16_t*)alloc((size_t)INF*HID*2);
  float*    bcomb  = (float*)   alloc((size_t)HID*4);
  uint32_t* h0s    = (uint32_t*)alloc((size_t)BAT*HID*4);
  uint32_t* h1s    = (uint32_t*)alloc((size_t)BAT*HID*4);
  uint32_t* ctr    = (uint32_t*)alloc(1024);

  // ---- prep ----
  wcomb_kernel<<<HID/16, 256, 0, stream>>>(W_ih, W_in, WcombF);
  bcomb_kernel<<<HID, 256, 0, stream>>>(W_ih, b_in, b_ih, bcomb);
  split_w<<<(HID*INF+255)/256, 256, 0, stream>>>(WcombF, Wc_hi, Wc_lo, HID*INF);
  split_w<<<(HID*HID+255)/256, 256, 0, stream>>>(W_ih + (size_t)HID*HID, Wih1_hi, Wih1_lo, HID*HID);
  split_w<<<(HID*HID+255)/256, 256, 0, stream>>>(W_hh, Whh0_hi, Whh0_lo, HID*HID);
  split_w<<<(HID*HID+255)/256, 256, 0, stream>>>(W_hh + (size_t)HID*HID, Whh1_hi, Whh1_lo, HID*HID);
  split_w<<<(INF*HID+255)/256, 256, 0, stream>>>(W_out, Wout_hi, Wout_lo, INF*HID);

  // ---- chunked pipeline ----
  for (int c = 0; c < nchunk; ++c){
    const float* xc = x + (size_t)c*T*BAT*INF;
    pack_x<<<T*BAT*INF/256, 256, 0, stream>>>(xc, xp, T*BAT*INF);
    // pre0 chunk = xp @ Wcomb^T + bcomb
    gemm_split<<<dim3(T*64/128, HID/128), 256, 0, stream>>>(xp, Wc_hi, Wc_lo, bcomb, pre0s, HID, INF);
    // wavefront scan over the chunk (both layers + pre1 fused)
    hipMemsetAsync(ctr, 0, 1024, stream);
    rnn_persist<<<NWG, 256, 0, stream>>>(
        pre0s, h0seq, pre1s, h1seq,
        Whh0_hi, Whh0_lo, Wih1_hi, Wih1_lo, Whh1_hi, Whh1_lo,
        b_hh, b_ih + HID, b_hh + HID, h0s, h1s, ctr, T, (c == 0) ? 1 : 0);
    // out chunk = h1chunk @ Wout^T + b_out
    gemm_split<<<dim3(T*64/128, INF/128), 256, 0, stream>>>(h1seq, Wout_hi, Wout_lo,
                                                            b_out, out + (size_t)c*T*BAT*INF, INF, HID);
  }
  extract_hidden<<<(2*BAT*HID)/256, 256, 0, stream>>>(h0s, h1s, out);
}

// Round 12
// 5499.825 us; speedup vs baseline: 2.0225x; 1.0212x over previous
//
#include <hip/hip_runtime.h>
#include <stdint.h>

#define SEQ 512
#define BAT 64
#define INF 256     // input features
#define HID 1024
#define SB  (SEQ*BAT)   // 32768 rows
#define G_WGS 64            // WGs per pipeline group
#define NWG (3*G_WGS)       // 192 persistent WGs

typedef __attribute__((ext_vector_type(8))) short short8;
typedef __attribute__((ext_vector_type(4))) float f32x4;

union Frag8 { uint32_t u[4]; short8 s; };

// ---------- numeric helpers: fp32 <-> (bf16 hi, bf16 lo) ----------
__device__ __forceinline__ uint32_t bf16hi_rne(uint32_t u){
  return (u + 0x7FFFu + ((u >> 16) & 1u)) & 0xFFFF0000u;
}
__device__ __forceinline__ uint32_t pack_split(float v){
  uint32_t hi = bf16hi_rne(__float_as_uint(v));
  float r = v - __uint_as_float(hi);
  uint32_t lo = bf16hi_rne(__float_as_uint(r)) >> 16;
  return hi | lo;                              // (hi16<<16) | lo16
}
__device__ __forceinline__ void unpack_pair(uint32_t u0, uint32_t u1,
                                            uint32_t& h, uint32_t& l){
  h = __builtin_amdgcn_perm(u1, u0, 0x07060302u);  // {u0.b2,u0.b3,u1.b2,u1.b3}
  l = __builtin_amdgcn_perm(u1, u0, 0x05040100u);  // {u0.b0,u0.b1,u1.b0,u1.b1}
}
__device__ __forceinline__ void gl16(const void* g, void* l){
  __builtin_amdgcn_global_load_lds(
      (const __attribute__((address_space(1))) void*)g,
      (__attribute__((address_space(3))) void*)l, 16, 0, 0);
}

// ---------- agent-scope atomics (flags + cross-WG visible writes) ----------
__device__ __forceinline__ void astore32(uint32_t* p, uint32_t v){
  __hip_atomic_store(p, v, __ATOMIC_RELAXED, __HIP_MEMORY_SCOPE_AGENT);
}
__device__ __forceinline__ void waitval(uint32_t* c, uint32_t tgt){
  unsigned spins = 0;
  while (__hip_atomic_load(c, __ATOMIC_RELAXED, __HIP_MEMORY_SCOPE_AGENT) < tgt){
    __builtin_amdgcn_s_sleep(1);
    if (++spins > (1u << 20)) break;   // failsafe: fail fast, never wedge
  }
}

// ---------- prep kernels ----------
__global__ __launch_bounds__(256) void wcomb_kernel(const float* __restrict__ A,
                                                    const float* __restrict__ B,
                                                    float* __restrict__ C){
  __shared__ float As[16][64];
  __shared__ float Bs[64][256];
  const int tid = threadIdx.x;
  const int g0 = blockIdx.x * 16;
  float acc[16];
#pragma unroll
  for (int g = 0; g < 16; ++g) acc[g] = 0.f;
  for (int h0 = 0; h0 < HID; h0 += 64){
    __syncthreads();
#pragma unroll
    for (int j = 0; j < 4; ++j){
      int c = j*256 + tid;
      As[c >> 6][c & 63] = A[(size_t)(g0 + (c >> 6))*HID + h0 + (c & 63)];
    }
#pragma unroll
    for (int j = 0; j < 64; ++j) Bs[j][tid] = B[(size_t)(h0 + j)*INF + tid];
    __syncthreads();
#pragma unroll
    for (int hh = 0; hh < 64; hh += 4){
      float b0 = Bs[hh][tid], b1 = Bs[hh+1][tid], b2 = Bs[hh+2][tid], b3 = Bs[hh+3][tid];
#pragma unroll
      for (int g = 0; g < 16; ++g){
        const float4 a = *(const float4*)&As[g][hh];
        acc[g] += a.x*b0 + a.y*b1 + a.z*b2 + a.w*b3;
      }
    }
  }
#pragma unroll
  for (int g = 0; g < 16; ++g) C[(size_t)(g0 + g)*INF + tid] = acc[g];
}

__global__ __launch_bounds__(256) void bcomb_kernel(const float* __restrict__ Wih0,
                                                    const float* __restrict__ bin,
                                                    const float* __restrict__ bih0,
                                                    float* __restrict__ bcomb){
  __shared__ float r[4];
  const int g = blockIdx.x, tid = threadIdx.x;
  float s = 0.f;
  for (int h = tid; h < HID; h += 256) s += Wih0[(size_t)g*HID + h] * bin[h];
  for (int o = 32; o > 0; o >>= 1) s += __shfl_down(s, o, 64);
  if ((tid & 63) == 0) r[tid >> 6] = s;
  __syncthreads();
  if (tid == 0) bcomb[g] = bih0[g] + r[0] + r[1] + r[2] + r[3];
}

__global__ void split_w(const float* __restrict__ in, uint16_t* __restrict__ hi,
                        uint16_t* __restrict__ lo, int n){
  int i = blockIdx.x*256 + threadIdx.x;
  if (i < n){
    float v = in[i];
    uint32_t h = bf16hi_rne(__float_as_uint(v));
    float r = v - __uint_as_float(h);
    hi[i] = (uint16_t)(h >> 16);
    lo[i] = (uint16_t)(bf16hi_rne(__float_as_uint(r)) >> 16);
  }
}

__global__ void pack_x(const float* __restrict__ in, uint32_t* __restrict__ out, int n){
  int i = blockIdx.x*256 + threadIdx.x;
  if (i < n) out[i] = pack_split(in[i]);
}

// ---------- batched split GEMM (pre0 / out): C = unpack(A) @ (Whi+Wlo)^T + bias ----------
__global__ __launch_bounds__(256) void gemm_split(
    const uint32_t* __restrict__ A, const uint16_t* __restrict__ Whi,
    const uint16_t* __restrict__ Wlo, const float* __restrict__ bias,
    float* __restrict__ C, int N, int K)
{
  __shared__ uint32_t Al[128*32];
  __shared__ uint16_t Wh[128*32];
  __shared__ uint16_t Wl[128*32];
  const int tid  = threadIdx.x;
  const int lane = tid & 63;
  const int w    = tid >> 6;
  const int wm   = w >> 1, wn = w & 1;
  const int lr   = lane & 15, kg = lane >> 4;
  const int bm   = blockIdx.x, bn = blockIdx.y;

  const uint32_t* Ag  = A   + (size_t)bm*128*K;
  const uint16_t* Whg = Whi + (size_t)bn*128*K;
  const uint16_t* Wlg = Wlo + (size_t)bn*128*K;

  f32x4 acc[4][4];
#pragma unroll
  for (int i = 0; i < 4; ++i)
#pragma unroll
    for (int j = 0; j < 4; ++j) acc[i][j] = (f32x4){0.f,0.f,0.f,0.f};

  for (int ks = 0; ks < K; ks += 32){
    __syncthreads();
#pragma unroll
    for (int j = 0; j < 4; ++j){
      int c = j*256 + tid;
      int row = c >> 3, kc = c & 7;
      int kcs = kc ^ ((row & 3) << 1);
      gl16(Ag + (size_t)row*K + ks + kcs*4, (char*)Al + c*16);
    }
#pragma unroll
    for (int j = 0; j < 2; ++j){
      int c = j*256 + tid;
      int row = c >> 2, kc = c & 3;
      int kcs = kc ^ (row & 3);
      gl16(Whg + (size_t)row*K + ks + kcs*8, (char*)Wh + c*16);
      gl16(Wlg + (size_t)row*K + ks + kcs*8, (char*)Wl + c*16);
    }
    __syncthreads();

    short8 ah[4], al[4];
#pragma unroll
    for (int mt = 0; mt < 4; ++mt){
      int row = wm*64 + mt*16 + lr;
      int c2  = kg ^ (row & 3);
      const uint32_t* p = &Al[row*32 + c2*8];
      uint4 a0 = *(const uint4*)p;
      uint4 a1 = *(const uint4*)(p + 4);
      Frag8 fh, fl;
      unpack_pair(a0.x, a0.y, fh.u[0], fl.u[0]);
      unpack_pair(a0.z, a0.w, fh.u[1], fl.u[1]);
      unpack_pair(a1.x, a1.y, fh.u[2], fl.u[2]);
      unpack_pair(a1.z, a1.w, fh.u[3], fl.u[3]);
      ah[mt] = fh.s; al[mt] = fl.s;
    }
#pragma unroll
    for (int nt = 0; nt < 4; ++nt){
      int row = wn*64 + nt*16 + lr;
      int kc  = kg ^ (row & 3);
      short8 whf = *(const short8*)&Wh[row*32 + kc*8];
      short8 wlf = *(const short8*)&Wl[row*32 + kc*8];
#pragma unroll
      for (int mt = 0; mt < 4; ++mt){
        acc[mt][nt] = __builtin_amdgcn_mfma_f32_16x16x32_bf16(ah[mt], whf, acc[mt][nt], 0,0,0);
        acc[mt][nt] = __builtin_amdgcn_mfma_f32_16x16x32_bf16(al[mt], whf, acc[mt][nt], 0,0,0);
        acc[mt][nt] = __builtin_amdgcn_mfma_f32_16x16x32_bf16(ah[mt], wlf, acc[mt][nt], 0,0,0);
      }
    }
  }
#pragma unroll
  for (int nt = 0; nt < 4; ++nt){
    int col = bn*128 + wn*64 + nt*16 + lr;
    float bv = bias[col];
#pragma unroll
    for (int mt = 0; mt < 4; ++mt){
#pragma unroll
      for (int r = 0; r < 4; ++r){
        int rowg = bm*128 + wm*64 + mt*16 + kg*4 + r;
        C[(size_t)rowg*N + col] = acc[mt][nt][r] + bv;
      }
    }
  }
}

// ---------- persistent wavefront scan ----------
// 192 WGs x 256 thr. group = wg/64: 0 = L0 rec (t=r), 1 = Wih1*h0 (t=r-1),
// 2 = L1 rec (t=r-2). sub=wg%64: rh=sub>>5 (32-row half), ci=sub&31 (32-col).
// W slice in LDS fragment-linear (128 KB). A: 16 chunks x 8 KB, 4 LDS slots,
// 3-deep prefetch, counted vmcnt(4/2/0), ONE s_barrier per chunk.
// Flags: per-group completion counter (atomic add) + 8 broadcast-replica
// lines; each consumer polls replica[wg&7] -> no single-line poll contention.
__global__ __launch_bounds__(256, 1) void rnn_persist(
    const float* __restrict__ pre0, uint32_t* __restrict__ h0seq,
    uint32_t* __restrict__ pre1, uint32_t* __restrict__ h1seq,
    const uint16_t* __restrict__ Whh0h, const uint16_t* __restrict__ Whh0l,
    const uint16_t* __restrict__ Wih1h, const uint16_t* __restrict__ Wih1l,
    const uint16_t* __restrict__ Whh1h, const uint16_t* __restrict__ Whh1l,
    const float* __restrict__ bhh0, const float* __restrict__ bih1,
    const float* __restrict__ bhh1,
    uint32_t* h0s, uint32_t* h1s,
    uint32_t* ctr, int T, int first)
{
  __shared__ short WhF[32768];        // 64 KB, fragment-linear
  __shared__ short WlF[32768];        // 64 KB
  __shared__ uint32_t Abuf[4][2048];  // 4 x 8 KB A chunks (total = exactly 160 KiB)
  const int tid  = threadIdx.x;
  const int lane = tid & 63;
  const int w    = tid >> 6;                 // 0..3
  const int mt   = w >> 1, ntw = w & 1;
  const int lr   = lane & 15, kg = lane >> 4;
  const int wg   = blockIdx.x;
  const int group = wg / G_WGS;              // 0,1,2
  const int sub  = wg % G_WGS;
  const int rh   = sub >> 5;                 // 0..1 (rows 32*rh)
  const int ci   = sub & 31;                 // 0..31 (cols 32*ci)
  const int col0 = ci * 32;

  // flag layout (u32 offsets): counters c_g @ g*64 (256B apart);
  // broadcast lines: 512 + g*512 + b*64  (8 lines x 256B per group)
  uint32_t* cmy  = ctr + group*64;
  uint32_t* bcmy = ctr + 512 + group*512;
  uint32_t* bc0  = ctr + 512 + 0*512 + (wg & 7)*64;
  uint32_t* bc1  = ctr + 512 + 1*512 + (wg & 7)*64;
  uint32_t* bc2  = ctr + 512 + 2*512 + (wg & 7)*64;

  const uint16_t* Whg = (group == 0) ? Whh0h : (group == 1) ? Wih1h : Whh1h;
  const uint16_t* Wlg = (group == 0) ? Whh0l : (group == 1) ? Wih1l : Whh1l;

  // ---- stage W slice into LDS once, fragment-linear ----
#pragma unroll
  for (int it = 0; it < 16; ++it){
    int lin = it*256 + tid;          // 0..4095
    int c = lin >> 7, j = lin & 127;
    int dst = (((c >> 4)*32 + (j >> 2))*64 + (j & 3)*16 + (c & 15))*8;
    *(uint4*)&WhF[dst] = *(const uint4*)&Whg[(size_t)(col0 + c)*HID + j*8];
    *(uint4*)&WlF[dst] = *(const uint4*)&Wlg[(size_t)(col0 + c)*HID + j*8];
  }
  __syncthreads();

  const int fragbase = ntw*16384 + lane*8;       // shorts; + ks*512
  const int arow = mt*16 + lr;                   // local A row this lane reads
  const int p3r  = ((arow & 3) << 1) | ((arow >> 2) & 1);

  const int col = col0 + ntw*16 + lr;
  const float bvg = (group == 0) ? bhh0[col]
                   : (group == 1) ? (bih1[col] + bhh1[col]) : 0.f;

  const int R = T + 2;
  for (int r = 0; r < R; ++r){
    const int t = r - group;
    const bool valid = (t >= 0 && t < T);

    // ---- dependency waits (replica polls; G2's two waits in parallel) ----
    if (valid){
      if (group == 0){
        if (tid == 0 && t > 0) waitval(bc0, (uint32_t)t);
      } else if (group == 1){
        if (tid == 0) waitval(bc0, (uint32_t)(t+1));
      } else {
        if (tid == 0) waitval(bc1, (uint32_t)(t+1));
        else if (tid == 64 && t > 0) waitval(bc2, (uint32_t)t);
      }
    }
    __syncthreads();
    asm volatile("" ::: "memory");

    if (valid){
      const uint32_t* Ap;
      if (group == 0)
        Ap = (t == 0) ? (first ? (const uint32_t*)0 : h0s)
                      : h0seq + (size_t)(t-1)*(BAT*HID);
      else if (group == 1)
        Ap = h0seq + (size_t)t*(BAT*HID);
      else
        Ap = (t == 0) ? (first ? (const uint32_t*)0 : h1s)
                      : h1seq + (size_t)(t-1)*(BAT*HID);

      // hoisted epilogue-input loads (overlap with DMA pipeline)
      const int rowb = rh*32 + mt*16 + kg*4;
      const size_t idx0 = (size_t)t*(BAT*HID) + (size_t)rowb*HID + col;
      float pv[4] = {0.f,0.f,0.f,0.f};
      if (group == 0){
#pragma unroll
        for (int q = 0; q < 4; ++q) pv[q] = pre0[idx0 + (size_t)q*HID];
      } else if (group == 2){
#pragma unroll
        for (int q = 0; q < 4; ++q) pv[q] = __uint_as_float(pre1[idx0 + (size_t)q*HID]);
      }

      f32x4 acc[4];
#pragma unroll
      for (int i = 0; i < 4; ++i) acc[i] = (f32x4){0.f,0.f,0.f,0.f};

      if (Ap){
        // chunk k (0..15): rows [rh*32,+32) x K-elems [k*64,+64) (8 KB).
        // slot s=0..511: row=s>>4, pos=s&15 (16B units); src pos ^= p3(row).
        auto STAGE = [&](int k){
          const int sl = k & 3;
#pragma unroll
          for (int j = 0; j < 2; ++j){
            const int slot  = w*128 + j*64 + lane;
            const int row_l = slot >> 4;
            const int pos   = slot & 15;
            const int p3 = ((row_l & 3) << 1) | ((row_l >> 2) & 1);
            const uint32_t* src = Ap + (size_t)(rh*32 + row_l)*HID + k*64 + (pos ^ p3)*4;
            gl16(src, (char*)&Abuf[sl][0] + (w*128 + j*64)*16 + lane*16);
          }
        };

        STAGE(0); STAGE(1); STAGE(2);
#pragma unroll
        for (int k = 0; k < 16; ++k){
          if (k < 14)      asm volatile("s_waitcnt vmcnt(4)" ::: "memory");
          else if (k == 14) asm volatile("s_waitcnt vmcnt(2)" ::: "memory");
          else              asm volatile("s_waitcnt vmcnt(0)" ::: "memory");
          __builtin_amdgcn_s_barrier();
          __builtin_amdgcn_sched_barrier(0);
          if (k < 13) STAGE(k+3);
          const uint32_t* Ab = &Abuf[k & 3][arow*64];
#pragma unroll
          for (int s2 = 0; s2 < 2; ++s2){
            const int ks = k*2 + s2;
            const int sA = ((s2 << 3) + (kg << 1)) ^ p3r;
            uint4 a0 = *(const uint4*)&Ab[sA*4];
            uint4 a1 = *(const uint4*)&Ab[(sA^1)*4];
            Frag8 fh, fl;
            unpack_pair(a0.x, a0.y, fh.u[0], fl.u[0]);
            unpack_pair(a0.z, a0.w, fh.u[1], fl.u[1]);
            unpack_pair(a1.x, a1.y, fh.u[2], fl.u[2]);
            unpack_pair(a1.z, a1.w, fh.u[3], fl.u[3]);
            short8 whf = *(const short8*)&WhF[fragbase + ks*512];
            short8 wlf = *(const short8*)&WlF[fragbase + ks*512];
            acc[ks & 3] = __builtin_amdgcn_mfma_f32_16x16x32_bf16(fh.s, whf, acc[ks & 3], 0,0,0);
            acc[ks & 3] = __builtin_amdgcn_mfma_f32_16x16x32_bf16(fl.s, whf, acc[ks & 3], 0,0,0);
            acc[ks & 3] = __builtin_amdgcn_mfma_f32_16x16x32_bf16(fh.s, wlf, acc[ks & 3], 0,0,0);
          }
        }
      }
      f32x4 s = (acc[0] + acc[1]) + (acc[2] + acc[3]);

      // ---- epilogue ----
      if (group == 0){
#pragma unroll
        for (int q = 0; q < 4; ++q){
          const size_t idx = idx0 + (size_t)q*HID;
          float v = tanhf(s[q] + pv[q] + bvg);
          uint32_t pk = pack_split(v);
          astore32(h0seq + idx, pk);
          if (t == T-1) astore32(h0s + (size_t)(rowb + q)*HID + col, pk);
        }
      } else if (group == 1){
#pragma unroll
        for (int q = 0; q < 4; ++q){
          const size_t idx = idx0 + (size_t)q*HID;
          astore32(pre1 + idx, __float_as_uint(s[q] + bvg));
        }
      } else {
#pragma unroll
        for (int q = 0; q < 4; ++q){
          const size_t idx = idx0 + (size_t)q*HID;
          float v = tanhf(s[q] + pv[q]);
          uint32_t pk = pack_split(v);
          astore32(h1seq + idx, pk);
          if (t == T-1) astore32(h1s + (size_t)(rowb + q)*HID + col, pk);
        }
      }
    }

    // drain stores to the coherence point, then signal + broadcast
    asm volatile("s_waitcnt vmcnt(0) lgkmcnt(0)" ::: "memory");
    __syncthreads();
    if (tid == 0 && valid){
      unsigned old = __hip_atomic_fetch_add(cmy, 1u, __ATOMIC_RELAXED, __HIP_MEMORY_SCOPE_AGENT);
      if (old + 1u == 64u * (unsigned)(t + 1)){   // last WG of this step
#pragma unroll
        for (int b = 0; b < 8; ++b) astore32(bcmy + b*64, (uint32_t)(t + 1));
      }
    }
  }
}

// ---------- hidden output from carried states ----------
__global__ void extract_hidden(const uint32_t* __restrict__ h0s,
                               const uint32_t* __restrict__ h1s,
                               float* __restrict__ out){
  int i = blockIdx.x*256 + threadIdx.x;   // 0..131071
  uint32_t p = (i >> 16) ? h1s[i & 65535] : h0s[i & 65535];
  out[(size_t)SB*INF + i] = __uint_as_float(p & 0xFFFF0000u) + __uint_as_float(p << 16);
}

// ---------- host ----------
extern "C" void kernel_launch(void* const* d_in, const int* in_sizes, int n_in,
                              void* d_out, int out_size, void* d_ws, size_t ws_size,
                              hipStream_t stream)
{
  const float* x    = (const float*)d_in[0];
  const float* W_in = (const float*)d_in[1];
  const float* b_in = (const float*)d_in[2];
  const float* W_ih = (const float*)d_in[3];   // [2][H][H]
  const float* W_hh = (const float*)d_in[4];   // [2][H][H]
  const float* b_ih = (const float*)d_in[5];   // [2][H]
  const float* b_hh = (const float*)d_in[6];   // [2][H]
  const float* W_out= (const float*)d_in[7];   // [I][H]
  const float* b_out= (const float*)d_in[8];
  float* out = (float*)d_out;
  (void)in_sizes; (void)n_in; (void)out_size;

  // ---- choose chunk length T to fit ws_size ----
  const size_t fixedB = 16257024 + 16384;
  const size_t perT   = 1114112;
  int T = 512;
  while (T > 2 && fixedB + (size_t)T*perT + 65536 > ws_size) T >>= 1;
  const int nchunk = SEQ / T;

  char* ws = (char*)d_ws;
  size_t off = 0;
  auto alloc = [&](size_t bytes)->void*{
    void* p = ws + off; off += (bytes + 255) & ~(size_t)255; return p;
  };
  float*    pre0s  = (float*)   alloc((size_t)T*BAT*HID*4);
  uint32_t* h0seq  = (uint32_t*)alloc((size_t)T*BAT*HID*4);
  uint32_t* pre1s  = (uint32_t*)alloc((size_t)T*BAT*HID*4);
  uint32_t* h1seq  = (uint32_t*)alloc((size_t)T*BAT*HID*4);
  uint32_t* xp     = (uint32_t*)alloc((size_t)T*BAT*INF*4);
  float*    WcombF = (float*)   alloc((size_t)HID*INF*4);
  uint16_t* Wc_hi  = (uint16_t*)alloc((size_t)HID*INF*2);
  uint16_t* Wc_lo  = (uint16_t*)alloc((size_t)HID*INF*2);
  uint16_t* Wih1_hi= (uint16_t*)alloc((size_t)HID*HID*2);
  uint16_t* Wih1_lo= (uint16_t*)alloc((size_t)HID*HID*2);
  uint16_t* Whh0_hi= (uint16_t*)alloc((size_t)HID*HID*2);
  uint16_t* Whh0_lo= (uint16_t*)alloc((size_t)HID*HID*2);
  uint16_t* Whh1_hi= (uint16_t*)alloc((size_t)HID*HID*2);
  uint16_t* Whh1_lo= (uint16_t*)alloc((size_t)HID*HID*2);
  uint16_t* Wout_hi= (uint16_t*)alloc((size_t)INF*HID*2);
  uint16_t* Wout_lo= (uint16_t*)alloc((size_t)INF*HID*2);
  float*    bcomb  = (float*)   alloc((size_t)HID*4);
  uint32_t* h0s    = (uint32_t*)alloc((size_t)BAT*HID*4);
  uint32_t* h1s    = (uint32_t*)alloc((size_t)BAT*HID*4);
  uint32_t* ctr    = (uint32_t*)alloc(8192);

  // ---- prep ----
  wcomb_kernel<<<HID/16, 256, 0, stream>>>(W_ih, W_in, WcombF);
  bcomb_kernel<<<HID, 256, 0, stream>>>(W_ih, b_in, b_ih, bcomb);
  split_w<<<(HID*INF+255)/256, 256, 0, stream>>>(WcombF, Wc_hi, Wc_lo, HID*INF);
  split_w<<<(HID*HID+255)/256, 256, 0, stream>>>(W_ih + (size_t)HID*HID, Wih1_hi, Wih1_lo, HID*HID);
  split_w<<<(HID*HID+255)/256, 256, 0, stream>>>(W_hh, Whh0_hi, Whh0_lo, HID*HID);
  split_w<<<(HID*HID+255)/256, 256, 0, stream>>>(W_hh + (size_t)HID*HID, Whh1_hi, Whh1_lo, HID*HID);
  split_w<<<(INF*HID+255)/256, 256, 0, stream>>>(W_out, Wout_hi, Wout_lo, INF*HID);

  // ---- chunked pipeline ----
  for (int c = 0; c < nchunk; ++c){
    const float* xc = x + (size_t)c*T*BAT*INF;
    pack_x<<<T*BAT*INF/256, 256, 0, stream>>>(xc, xp, T*BAT*INF);
    // pre0 chunk = xp @ Wcomb^T + bcomb
    gemm_split<<<dim3(T*64/128, HID/128), 256, 0, stream>>>(xp, Wc_hi, Wc_lo, bcomb, pre0s, HID, INF);
    // wavefront scan over the chunk (both layers + pre1 fused)
    hipMemsetAsync(ctr, 0, 8192, stream);
    rnn_persist<<<NWG, 256, 0, stream>>>(
        pre0s, h0seq, pre1s, h1seq,
        Whh0_hi, Whh0_lo, Wih1_hi, Wih1_lo, Whh1_hi, Whh1_lo,
        b_hh, b_ih + HID, b_hh + HID, h0s, h1s, ctr, T, (c == 0) ? 1 : 0);
    // out chunk = h1chunk @ Wout^T + b_out
    gemm_split<<<dim3(T*64/128, INF/128), 256, 0, stream>>>(h1seq, Wout_hi, Wout_lo,
                                                            b_out, out + (size_t)c*T*BAT*INF, INF, HID);
  }
  extract_hidden<<<(2*BAT*HID)/256, 256, 0, stream>>>(h0s, h1s, out);
}